// Round 1
// baseline (540.125 us; speedup 1.0000x reference)
//
#include <hip/hip_runtime.h>
#include <cstdint>
#include <cstddef>

// GAT forward on MI355X.
// h = x@W (f32 vector ALU; no f32 MFMA on CDNA4), fused per-node logits,
// single edge pass with unnormalized accumulation (softmax division deferred
// to finalize since s[dst,head] is a per-destination scalar), ELU epilogue.

// ---------------- Kernel 1: linear + logits ----------------
// Block: 256 threads (4 waves). W (128x64 f32 = 32 KB) staged in LDS once.
// Each iteration stages 16 x-rows (8 KB); each thread computes 4 nodes of
// one output column; a_src/a_dst reduced via shfl_xor within 8-lane f-groups.
__global__ __launch_bounds__(256) void gat_linear(
    const float* __restrict__ x, const float* __restrict__ W,
    const float* __restrict__ att_src, const float* __restrict__ att_dst,
    float* __restrict__ h, float* __restrict__ a_src, float* __restrict__ a_dst,
    int N)
{
    __shared__ float Wl[128 * 64];   // 32 KB
    __shared__ float xl[16][128];    //  8 KB
    const int tid  = threadIdx.x;
    const int lane = tid & 63;
    const int wi   = tid >> 6;

    for (int i = tid; i < 2048; i += 256)
        reinterpret_cast<float4*>(Wl)[i] = reinterpret_cast<const float4*>(W)[i];
    const float atts = att_src[lane];
    const float attd = att_dst[lane];

    for (int nb = blockIdx.x * 16; nb < N; nb += gridDim.x * 16) {
        __syncthreads();  // previous-iter xl reads done (also fences Wl on iter 0)
        for (int i = tid; i < 512; i += 256) {
            int r = i >> 5, k4 = i & 31;
            int node = nb + r;
            if (node < N)
                reinterpret_cast<float4*>(xl[r])[k4] =
                    reinterpret_cast<const float4*>(x + (size_t)node * 128)[k4];
        }
        __syncthreads();

        float acc0 = 0.f, acc1 = 0.f, acc2 = 0.f, acc3 = 0.f;
        const int r0 = wi * 4;
        const float* xr0 = xl[r0 + 0];
        const float* xr1 = xl[r0 + 1];
        const float* xr2 = xl[r0 + 2];
        const float* xr3 = xl[r0 + 3];
        #pragma unroll 8
        for (int k = 0; k < 128; ++k) {
            float wv = Wl[k * 64 + lane];  // lanes 0..63 -> 2-way bank alias (free)
            acc0 += xr0[k] * wv;           // broadcast reads (free)
            acc1 += xr1[k] * wv;
            acc2 += xr2[k] * wv;
            acc3 += xr3[k] * wv;
        }

        float accs[4] = {acc0, acc1, acc2, acc3};
        #pragma unroll
        for (int j = 0; j < 4; ++j) {
            int node = nb + r0 + j;
            if (node < N) {
                h[(size_t)node * 64 + lane] = accs[j];
                float vs = accs[j] * atts;
                float vd = accs[j] * attd;
                vs += __shfl_xor(vs, 1, 64); vd += __shfl_xor(vd, 1, 64);
                vs += __shfl_xor(vs, 2, 64); vd += __shfl_xor(vd, 2, 64);
                vs += __shfl_xor(vs, 4, 64); vd += __shfl_xor(vd, 4, 64);
                if ((lane & 7) == 0) {
                    a_src[node * 8 + (lane >> 3)] = vs;
                    a_dst[node * 8 + (lane >> 3)] = vd;
                }
            }
        }
    }
}

// ---------------- Kernel 2: edge pass ----------------
// One wave per (edge or self-loop). lane = head*8 + f.
// w = exp(leaky_relu(a_src[src,h] + a_dst[dst,h], 0.2))  (no max-shift: values
// are ~N(0,2), max over 13.6M samples ~9, exp safe in f32; shift cancels in
// the deferred normalization anyway).
// Accumulate w*h[src] into out[dst] (64 f32 atomics) and w into s[dst,h].
__global__ __launch_bounds__(256) void gat_edge(
    const int* __restrict__ e_src, const int* __restrict__ e_dst,
    const float* __restrict__ h, const float* __restrict__ a_src,
    const float* __restrict__ a_dst, float* __restrict__ out_acc,
    float* __restrict__ s_sum, int N, int E)
{
    const int lane = threadIdx.x & 63;
    const int head = lane >> 3;
    const long long total = (long long)E + N;
    long long ew = (long long)blockIdx.x * 4 + (threadIdx.x >> 6);
    if (ew >= total) return;

    int src, dst;
    if (ew < E) { src = e_src[ew]; dst = e_dst[ew]; }
    else        { src = dst = (int)(ew - E); }   // self-loop

    float e = a_src[src * 8 + head] + a_dst[dst * 8 + head];
    e = e > 0.f ? e : 0.2f * e;
    float w = __expf(e);
    float hv = h[(size_t)src * 64 + lane];
    atomicAdd(&out_acc[(size_t)dst * 64 + lane], w * hv);
    if ((lane & 7) == 0)
        atomicAdd(&s_sum[dst * 8 + head], w);
}

// ---------------- Kernel 3: finalize ----------------
// out = elu(acc / (s + 1e-16) + bias)
__global__ __launch_bounds__(256) void gat_finalize(
    float* __restrict__ out, const float* __restrict__ s_sum,
    const float* __restrict__ bias, int N)
{
    int i = blockIdx.x * 256 + threadIdx.x;
    if (i >= N * 64) return;
    int node = i >> 6, c = i & 63;
    float v = out[i] / (s_sum[node * 8 + (c >> 3)] + 1e-16f);
    v += bias[c];
    out[i] = v > 0.f ? v : expm1f(v);
}

extern "C" void kernel_launch(void* const* d_in, const int* in_sizes, int n_in,
                              void* d_out, int out_size, void* d_ws, size_t ws_size,
                              hipStream_t stream)
{
    const float* x       = (const float*)d_in[0];
    const float* W       = (const float*)d_in[1];
    const float* att_src = (const float*)d_in[2];
    const float* att_dst = (const float*)d_in[3];
    const float* bias    = (const float*)d_in[4];
    const int*   ei      = (const int*)d_in[5];   // int32 (JAX x64 disabled)

    const int N = in_sizes[0] / 128;
    const int E = in_sizes[5] / 2;

    float* out   = (float*)d_out;
    float* h     = (float*)d_ws;                  // N*64 f32
    float* a_src = h + (size_t)N * 64;            // N*8
    float* a_dst = a_src + (size_t)N * 8;         // N*8
    float* s_sum = a_dst + (size_t)N * 8;         // N*8

    hipMemsetAsync(d_out, 0, (size_t)N * 64 * sizeof(float), stream);
    hipMemsetAsync(s_sum, 0, (size_t)N * 8 * sizeof(float), stream);

    gat_linear<<<1024, 256, 0, stream>>>(x, W, att_src, att_dst, h, a_src, a_dst, N);

    long long total = (long long)E + N;
    int eblocks = (int)((total + 3) / 4);
    gat_edge<<<eblocks, 256, 0, stream>>>(ei, ei + E, h, a_src, a_dst, out, s_sum, N, E);

    int fblocks = (N * 64 + 255) / 256;
    gat_finalize<<<fblocks, 256, 0, stream>>>(out, s_sum, bias, N);
}

// Round 2
// 439.284 us; speedup vs baseline: 1.2296x; 1.2296x over previous
//
#include <hip/hip_runtime.h>
#include <cstdint>
#include <cstddef>

// GAT forward on MI355X — CSR-gather formulation (no f32 atomics).
// h = x@W (f32 vector ALU), per-node logits fused into the linear kernel.
// Edge aggregation: build CSR by dst on device, then one wave per dst node
// accumulates unnormalized sum(w*h[src]) and sum(w) in registers; softmax
// division, bias and ELU fused into the gather epilogue.

// ---------------- Kernel 1: linear + logits ----------------
__global__ __launch_bounds__(256) void gat_linear(
    const float* __restrict__ x, const float* __restrict__ W,
    const float* __restrict__ att_src, const float* __restrict__ att_dst,
    float* __restrict__ h, float* __restrict__ a_src, float* __restrict__ a_dst,
    int N)
{
    __shared__ float Wl[128 * 64];   // 32 KB
    __shared__ float xl[16][128];    //  8 KB
    const int tid  = threadIdx.x;
    const int lane = tid & 63;
    const int wi   = tid >> 6;

    for (int i = tid; i < 2048; i += 256)
        reinterpret_cast<float4*>(Wl)[i] = reinterpret_cast<const float4*>(W)[i];
    const float atts = att_src[lane];
    const float attd = att_dst[lane];

    for (int nb = blockIdx.x * 16; nb < N; nb += gridDim.x * 16) {
        __syncthreads();
        for (int i = tid; i < 512; i += 256) {
            int r = i >> 5, k4 = i & 31;
            int node = nb + r;
            if (node < N)
                reinterpret_cast<float4*>(xl[r])[k4] =
                    reinterpret_cast<const float4*>(x + (size_t)node * 128)[k4];
        }
        __syncthreads();

        float acc0 = 0.f, acc1 = 0.f, acc2 = 0.f, acc3 = 0.f;
        const int r0 = wi * 4;
        const float* xr0 = xl[r0 + 0];
        const float* xr1 = xl[r0 + 1];
        const float* xr2 = xl[r0 + 2];
        const float* xr3 = xl[r0 + 3];
        #pragma unroll 8
        for (int k = 0; k < 128; ++k) {
            float wv = Wl[k * 64 + lane];
            acc0 += xr0[k] * wv;
            acc1 += xr1[k] * wv;
            acc2 += xr2[k] * wv;
            acc3 += xr3[k] * wv;
        }

        float accs[4] = {acc0, acc1, acc2, acc3};
        #pragma unroll
        for (int j = 0; j < 4; ++j) {
            int node = nb + r0 + j;
            if (node < N) {
                h[(size_t)node * 64 + lane] = accs[j];
                float vs = accs[j] * atts;
                float vd = accs[j] * attd;
                vs += __shfl_xor(vs, 1, 64); vd += __shfl_xor(vd, 1, 64);
                vs += __shfl_xor(vs, 2, 64); vd += __shfl_xor(vd, 2, 64);
                vs += __shfl_xor(vs, 4, 64); vd += __shfl_xor(vd, 4, 64);
                if ((lane & 7) == 0) {
                    a_src[node * 8 + (lane >> 3)] = vs;
                    a_dst[node * 8 + (lane >> 3)] = vd;
                }
            }
        }
    }
}

// ---------------- CSR build ----------------
__global__ __launch_bounds__(256) void gat_hist(
    const int* __restrict__ e_dst, int* __restrict__ deg, int E)
{
    int i = blockIdx.x * 256 + threadIdx.x;
    if (i < E) atomicAdd(&deg[e_dst[i]], 1);
}

// Per-chunk (1024 elems) exclusive scan; chunkSum[b] = chunk total.
__global__ __launch_bounds__(256) void gat_scan_chunks(
    const int* __restrict__ deg, int* __restrict__ off,
    int* __restrict__ chunkSum, int N)
{
    __shared__ int lds[256];
    const int t = threadIdx.x;
    const int base = blockIdx.x * 1024 + t * 4;
    int v0 = 0, v1 = 0, v2 = 0, v3 = 0;
    if (base + 0 < N) v0 = deg[base + 0];
    if (base + 1 < N) v1 = deg[base + 1];
    if (base + 2 < N) v2 = deg[base + 2];
    if (base + 3 < N) v3 = deg[base + 3];
    int s = v0 + v1 + v2 + v3;
    lds[t] = s;
    __syncthreads();
    #pragma unroll
    for (int d = 1; d < 256; d <<= 1) {
        int add = (t >= d) ? lds[t - d] : 0;
        __syncthreads();
        lds[t] += add;
        __syncthreads();
    }
    if (t == 255) chunkSum[blockIdx.x] = lds[255];
    int p = lds[t] - s;  // exclusive within chunk
    if (base + 0 < N) off[base + 0] = p; p += v0;
    if (base + 1 < N) off[base + 1] = p; p += v1;
    if (base + 2 < N) off[base + 2] = p; p += v2;
    if (base + 3 < N) off[base + 3] = p;
}

__global__ void gat_scan_tops(const int* __restrict__ chunkSum,
                              int* __restrict__ chunkBase,
                              int* __restrict__ off, int nChunks, int N)
{
    if (threadIdx.x == 0 && blockIdx.x == 0) {
        int run = 0;
        for (int i = 0; i < nChunks; ++i) { chunkBase[i] = run; run += chunkSum[i]; }
        off[N] = run;
    }
}

__global__ __launch_bounds__(256) void gat_add_base(
    int* __restrict__ off, int* __restrict__ cursor,
    const int* __restrict__ chunkBase, int N)
{
    int i = blockIdx.x * 256 + threadIdx.x;
    if (i < N) {
        int v = off[i] + chunkBase[i >> 10];
        off[i] = v;
        cursor[i] = v;
    }
}

__global__ __launch_bounds__(256) void gat_fill(
    const int* __restrict__ e_src, const int* __restrict__ e_dst,
    int* __restrict__ cursor, int* __restrict__ esrc, int E)
{
    int i = blockIdx.x * 256 + threadIdx.x;
    if (i < E) {
        int pos = atomicAdd(&cursor[e_dst[i]], 1);
        esrc[pos] = e_src[i];
    }
}

// ---------------- Kernel 2: gather + softmax + ELU ----------------
// One wave per dst node; lane = head*8 + f. Self-loop handled in init.
__global__ __launch_bounds__(256) void gat_gather(
    const int* __restrict__ off, const int* __restrict__ esrc,
    const float* __restrict__ h, const float* __restrict__ a_src,
    const float* __restrict__ a_dst, const float* __restrict__ bias,
    float* __restrict__ out, int N)
{
    const int node = blockIdx.x * 4 + (threadIdx.x >> 6);
    if (node >= N) return;
    const int lane = threadIdx.x & 63;
    const int head = lane >> 3;

    const float ad = a_dst[node * 8 + head];
    // self-loop
    float e0 = a_src[node * 8 + head] + ad;
    e0 = e0 > 0.f ? e0 : 0.2f * e0;
    float w = __expf(e0);
    float acc = w * h[(size_t)node * 64 + lane];
    float s = w;

    const int beg = off[node], end = off[node + 1];
    for (int k = beg; k < end; ++k) {
        int src = esrc[k];
        float e = a_src[src * 8 + head] + ad;
        e = e > 0.f ? e : 0.2f * e;
        float wk = __expf(e);
        acc += wk * h[(size_t)src * 64 + lane];
        s += wk;
    }

    float v = acc / (s + 1e-16f) + bias[lane];
    out[(size_t)node * 64 + lane] = v > 0.f ? v : expm1f(v);
}

extern "C" void kernel_launch(void* const* d_in, const int* in_sizes, int n_in,
                              void* d_out, int out_size, void* d_ws, size_t ws_size,
                              hipStream_t stream)
{
    const float* x       = (const float*)d_in[0];
    const float* W       = (const float*)d_in[1];
    const float* att_src = (const float*)d_in[2];
    const float* att_dst = (const float*)d_in[3];
    const float* bias    = (const float*)d_in[4];
    const int*   ei      = (const int*)d_in[5];   // int32 (JAX x64 disabled)

    const int N = in_sizes[0] / 128;
    const int E = in_sizes[5] / 2;
    const int nChunks = (N + 1023) / 1024;

    float* out = (float*)d_out;

    // workspace layout (all 4-byte elems)
    float* h        = (float*)d_ws;                    // N*64
    float* a_src    = h + (size_t)N * 64;              // N*8
    float* a_dst    = a_src + (size_t)N * 8;           // N*8
    int*   deg      = (int*)(a_dst + (size_t)N * 8);   // N
    int*   off      = deg + N;                         // N+1
    int*   cursor   = off + N + 1;                     // N
    int*   chunkSum = cursor + N;                      // nChunks
    int*   chunkBase= chunkSum + nChunks;              // nChunks
    int*   esrc     = chunkBase + nChunks;             // E

    const int* e_src = ei;
    const int* e_dst = ei + E;

    hipMemsetAsync(deg, 0, (size_t)N * sizeof(int), stream);

    gat_linear<<<1024, 256, 0, stream>>>(x, W, att_src, att_dst, h, a_src, a_dst, N);

    int eb = (E + 255) / 256;
    gat_hist<<<eb, 256, 0, stream>>>(e_dst, deg, E);
    gat_scan_chunks<<<nChunks, 256, 0, stream>>>(deg, off, chunkSum, N);
    gat_scan_tops<<<1, 64, 0, stream>>>(chunkSum, chunkBase, off, nChunks, N);
    gat_add_base<<<(N + 255) / 256, 256, 0, stream>>>(off, cursor, chunkBase, N);
    gat_fill<<<eb, 256, 0, stream>>>(e_src, e_dst, cursor, esrc, E);

    gat_gather<<<(N + 3) / 4, 256, 0, stream>>>(off, esrc, h, a_src, a_dst, bias, out, N);
}

// Round 3
// 354.101 us; speedup vs baseline: 1.5253x; 1.2406x over previous
//
#include <hip/hip_runtime.h>
#include <cstdint>
#include <cstddef>

// GAT forward on MI355X — CSR-gather formulation (no f32 atomics).
// Round 3: gather unrolled x4 (MLP), linear with float4 broadcast LDS reads,
// parallel top-level scan, vectorized hist/fill.

// ---------------- Kernel 1: linear + logits ----------------
__global__ __launch_bounds__(256) void gat_linear(
    const float* __restrict__ x, const float* __restrict__ W,
    const float* __restrict__ att_src, const float* __restrict__ att_dst,
    float* __restrict__ h, float* __restrict__ a_src, float* __restrict__ a_dst,
    int N)
{
    __shared__ float Wl[128 * 64];   // 32 KB
    __shared__ float xl[16][128];    //  8 KB
    const int tid  = threadIdx.x;
    const int lane = tid & 63;
    const int wi   = tid >> 6;

    for (int i = tid; i < 2048; i += 256)
        reinterpret_cast<float4*>(Wl)[i] = reinterpret_cast<const float4*>(W)[i];
    const float atts = att_src[lane];
    const float attd = att_dst[lane];

    for (int nb = blockIdx.x * 16; nb < N; nb += gridDim.x * 16) {
        __syncthreads();
        for (int i = tid; i < 512; i += 256) {
            int r = i >> 5, k4 = i & 31;
            int node = nb + r;
            if (node < N)
                reinterpret_cast<float4*>(xl[r])[k4] =
                    reinterpret_cast<const float4*>(x + (size_t)node * 128)[k4];
        }
        __syncthreads();

        float acc0 = 0.f, acc1 = 0.f, acc2 = 0.f, acc3 = 0.f;
        const int r0 = wi * 4;
        const float4* xr0 = reinterpret_cast<const float4*>(xl[r0 + 0]);
        const float4* xr1 = reinterpret_cast<const float4*>(xl[r0 + 1]);
        const float4* xr2 = reinterpret_cast<const float4*>(xl[r0 + 2]);
        const float4* xr3 = reinterpret_cast<const float4*>(xl[r0 + 3]);
        #pragma unroll 4
        for (int k4 = 0; k4 < 32; ++k4) {
            float4 x0 = xr0[k4];   // broadcast reads (same addr across lanes)
            float4 x1 = xr1[k4];
            float4 x2 = xr2[k4];
            float4 x3 = xr3[k4];
            const int kb = k4 * 4;
            float wa = Wl[(kb + 0) * 64 + lane];
            float wb = Wl[(kb + 1) * 64 + lane];
            float wc = Wl[(kb + 2) * 64 + lane];
            float wd = Wl[(kb + 3) * 64 + lane];
            acc0 += x0.x * wa + x0.y * wb + x0.z * wc + x0.w * wd;
            acc1 += x1.x * wa + x1.y * wb + x1.z * wc + x1.w * wd;
            acc2 += x2.x * wa + x2.y * wb + x2.z * wc + x2.w * wd;
            acc3 += x3.x * wa + x3.y * wb + x3.z * wc + x3.w * wd;
        }

        float accs[4] = {acc0, acc1, acc2, acc3};
        #pragma unroll
        for (int j = 0; j < 4; ++j) {
            int node = nb + r0 + j;
            if (node < N) {
                h[(size_t)node * 64 + lane] = accs[j];
                float vs = accs[j] * atts;
                float vd = accs[j] * attd;
                vs += __shfl_xor(vs, 1, 64); vd += __shfl_xor(vd, 1, 64);
                vs += __shfl_xor(vs, 2, 64); vd += __shfl_xor(vd, 2, 64);
                vs += __shfl_xor(vs, 4, 64); vd += __shfl_xor(vd, 4, 64);
                if ((lane & 7) == 0) {
                    a_src[node * 8 + (lane >> 3)] = vs;
                    a_dst[node * 8 + (lane >> 3)] = vd;
                }
            }
        }
    }
}

// ---------------- CSR build ----------------
__global__ __launch_bounds__(256) void gat_hist(
    const int* __restrict__ e_dst, int* __restrict__ deg, int E)
{
    int i = blockIdx.x * 256 + threadIdx.x;
    int b = i * 4;
    if (b + 3 < E) {
        int4 d = *reinterpret_cast<const int4*>(e_dst + b);
        atomicAdd(&deg[d.x], 1);
        atomicAdd(&deg[d.y], 1);
        atomicAdd(&deg[d.z], 1);
        atomicAdd(&deg[d.w], 1);
    } else {
        for (int k = b; k < E; ++k) atomicAdd(&deg[e_dst[k]], 1);
    }
}

// Per-chunk (1024 elems) exclusive scan; chunkSum[b] = chunk total.
__global__ __launch_bounds__(256) void gat_scan_chunks(
    const int* __restrict__ deg, int* __restrict__ off,
    int* __restrict__ chunkSum, int N)
{
    __shared__ int lds[256];
    const int t = threadIdx.x;
    const int base = blockIdx.x * 1024 + t * 4;
    int v0 = 0, v1 = 0, v2 = 0, v3 = 0;
    if (base + 0 < N) v0 = deg[base + 0];
    if (base + 1 < N) v1 = deg[base + 1];
    if (base + 2 < N) v2 = deg[base + 2];
    if (base + 3 < N) v3 = deg[base + 3];
    int s = v0 + v1 + v2 + v3;
    lds[t] = s;
    __syncthreads();
    #pragma unroll
    for (int d = 1; d < 256; d <<= 1) {
        int add = (t >= d) ? lds[t - d] : 0;
        __syncthreads();
        lds[t] += add;
        __syncthreads();
    }
    if (t == 255) chunkSum[blockIdx.x] = lds[255];
    int p = lds[t] - s;  // exclusive within chunk
    if (base + 0 < N) off[base + 0] = p; p += v0;
    if (base + 1 < N) off[base + 1] = p; p += v1;
    if (base + 2 < N) off[base + 2] = p; p += v2;
    if (base + 3 < N) off[base + 3] = p;
}

// Exclusive scan of chunk sums (nChunks <= 128) in one 128-thread block.
__global__ __launch_bounds__(128) void gat_scan_tops(
    const int* __restrict__ chunkSum, int* __restrict__ chunkBase,
    int* __restrict__ off, int nChunks, int N)
{
    __shared__ int lds[128];
    const int t = threadIdx.x;
    if (nChunks > 128) {               // safety fallback (not hit at N=100k)
        if (t == 0) {
            int run = 0;
            for (int i = 0; i < nChunks; ++i) { chunkBase[i] = run; run += chunkSum[i]; }
            off[N] = run;
        }
        return;
    }
    int v = (t < nChunks) ? chunkSum[t] : 0;
    lds[t] = v;
    __syncthreads();
    #pragma unroll
    for (int d = 1; d < 128; d <<= 1) {
        int add = (t >= d) ? lds[t - d] : 0;
        __syncthreads();
        lds[t] += add;
        __syncthreads();
    }
    if (t < nChunks) chunkBase[t] = lds[t] - v;
    if (t == nChunks - 1) off[N] = lds[t];
}

__global__ __launch_bounds__(256) void gat_add_base(
    int* __restrict__ off, int* __restrict__ cursor,
    const int* __restrict__ chunkBase, int N)
{
    int i = blockIdx.x * 256 + threadIdx.x;
    if (i < N) {
        int v = off[i] + chunkBase[i >> 10];
        off[i] = v;
        cursor[i] = v;
    }
}

__global__ __launch_bounds__(256) void gat_fill(
    const int* __restrict__ e_src, const int* __restrict__ e_dst,
    int* __restrict__ cursor, int* __restrict__ esrc, int E)
{
    int i = blockIdx.x * 256 + threadIdx.x;
    int b = i * 4;
    if (b + 3 < E) {
        int4 sv = *reinterpret_cast<const int4*>(e_src + b);
        int4 dv = *reinterpret_cast<const int4*>(e_dst + b);
        esrc[atomicAdd(&cursor[dv.x], 1)] = sv.x;
        esrc[atomicAdd(&cursor[dv.y], 1)] = sv.y;
        esrc[atomicAdd(&cursor[dv.z], 1)] = sv.z;
        esrc[atomicAdd(&cursor[dv.w], 1)] = sv.w;
    } else {
        for (int k = b; k < E; ++k)
            esrc[atomicAdd(&cursor[e_dst[k]], 1)] = e_src[k];
    }
}

// ---------------- Kernel 2: gather + softmax + ELU ----------------
// One wave per dst node; lane = head*8 + f. Edge loop unrolled x4 for MLP.
__global__ __launch_bounds__(256) void gat_gather(
    const int* __restrict__ off, const int* __restrict__ esrc,
    const float* __restrict__ h, const float* __restrict__ a_src,
    const float* __restrict__ a_dst, const float* __restrict__ bias,
    float* __restrict__ out, int N)
{
    const int node = blockIdx.x * 4 + (threadIdx.x >> 6);
    if (node >= N) return;
    const int lane = threadIdx.x & 63;
    const int head = lane >> 3;

    const float ad = a_dst[node * 8 + head];
    // self-loop
    float e0 = a_src[node * 8 + head] + ad;
    e0 = e0 > 0.f ? e0 : 0.2f * e0;
    float w0 = __expf(e0);
    float acc = w0 * h[(size_t)node * 64 + lane];
    float s = w0;

    const int beg = off[node], end = off[node + 1];
    int k = beg;
    for (; k + 4 <= end; k += 4) {
        const int s0 = esrc[k + 0];
        const int s1 = esrc[k + 1];
        const int s2 = esrc[k + 2];
        const int s3 = esrc[k + 3];
        float a0 = a_src[s0 * 8 + head];
        float a1 = a_src[s1 * 8 + head];
        float a2 = a_src[s2 * 8 + head];
        float a3 = a_src[s3 * 8 + head];
        float h0 = h[(size_t)s0 * 64 + lane];
        float h1 = h[(size_t)s1 * 64 + lane];
        float h2 = h[(size_t)s2 * 64 + lane];
        float h3 = h[(size_t)s3 * 64 + lane];
        a0 += ad; a0 = a0 > 0.f ? a0 : 0.2f * a0; float w0_ = __expf(a0);
        a1 += ad; a1 = a1 > 0.f ? a1 : 0.2f * a1; float w1_ = __expf(a1);
        a2 += ad; a2 = a2 > 0.f ? a2 : 0.2f * a2; float w2_ = __expf(a2);
        a3 += ad; a3 = a3 > 0.f ? a3 : 0.2f * a3; float w3_ = __expf(a3);
        acc += w0_ * h0; s += w0_;
        acc += w1_ * h1; s += w1_;
        acc += w2_ * h2; s += w2_;
        acc += w3_ * h3; s += w3_;
    }
    for (; k < end; ++k) {
        int src = esrc[k];
        float a = a_src[src * 8 + head] + ad;
        a = a > 0.f ? a : 0.2f * a;
        float wk = __expf(a);
        acc += wk * h[(size_t)src * 64 + lane];
        s += wk;
    }

    float v = acc / (s + 1e-16f) + bias[lane];
    out[(size_t)node * 64 + lane] = v > 0.f ? v : expm1f(v);
}

extern "C" void kernel_launch(void* const* d_in, const int* in_sizes, int n_in,
                              void* d_out, int out_size, void* d_ws, size_t ws_size,
                              hipStream_t stream)
{
    const float* x       = (const float*)d_in[0];
    const float* W       = (const float*)d_in[1];
    const float* att_src = (const float*)d_in[2];
    const float* att_dst = (const float*)d_in[3];
    const float* bias    = (const float*)d_in[4];
    const int*   ei      = (const int*)d_in[5];   // int32 (JAX x64 disabled)

    const int N = in_sizes[0] / 128;
    const int E = in_sizes[5] / 2;
    const int nChunks = (N + 1023) / 1024;

    float* out = (float*)d_out;

    // workspace layout (all 4-byte elems)
    float* h        = (float*)d_ws;                    // N*64
    float* a_src    = h + (size_t)N * 64;              // N*8
    float* a_dst    = a_src + (size_t)N * 8;           // N*8
    int*   deg      = (int*)(a_dst + (size_t)N * 8);   // N
    int*   off      = deg + N;                         // N+1
    int*   cursor   = off + N + 1;                     // N
    int*   chunkSum = cursor + N;                      // nChunks
    int*   chunkBase= chunkSum + nChunks;              // nChunks
    int*   esrc     = chunkBase + nChunks;             // E

    const int* e_src = ei;
    const int* e_dst = ei + E;

    hipMemsetAsync(deg, 0, (size_t)N * sizeof(int), stream);

    gat_linear<<<1024, 256, 0, stream>>>(x, W, att_src, att_dst, h, a_src, a_dst, N);

    int eb4 = (E / 4 + 256) / 256;
    gat_hist<<<eb4, 256, 0, stream>>>(e_dst, deg, E);
    gat_scan_chunks<<<nChunks, 256, 0, stream>>>(deg, off, chunkSum, N);
    gat_scan_tops<<<1, 128, 0, stream>>>(chunkSum, chunkBase, off, nChunks, N);
    gat_add_base<<<(N + 255) / 256, 256, 0, stream>>>(off, cursor, chunkBase, N);
    gat_fill<<<eb4, 256, 0, stream>>>(e_src, e_dst, cursor, esrc, E);

    gat_gather<<<(N + 3) / 4, 256, 0, stream>>>(off, esrc, h, a_src, a_dst, bias, out, N);
}

// Round 5
// 293.718 us; speedup vs baseline: 1.8389x; 1.2056x over previous
//
#include <hip/hip_runtime.h>
#include <cstdint>
#include <cstddef>

// GAT forward on MI355X — CSR-gather formulation (no f32 atomics).
// Round 5: fix gat_fill chunk stride (1024 edges/block, was 4096 -> 3/4 of
// esrc left poisoned -> OOB crash). dst-range-partitioned fill + masked
// unroll-8 gather otherwise unchanged from round 4.

// ---------------- Kernel 1: linear + logits ----------------
__global__ __launch_bounds__(256) void gat_linear(
    const float* __restrict__ x, const float* __restrict__ W,
    const float* __restrict__ att_src, const float* __restrict__ att_dst,
    float* __restrict__ h, float* __restrict__ a_src, float* __restrict__ a_dst,
    int N)
{
    __shared__ float Wl[128 * 64];   // 32 KB
    __shared__ float xl[16][128];    //  8 KB
    const int tid  = threadIdx.x;
    const int lane = tid & 63;
    const int wi   = tid >> 6;

    for (int i = tid; i < 2048; i += 256)
        reinterpret_cast<float4*>(Wl)[i] = reinterpret_cast<const float4*>(W)[i];
    const float atts = att_src[lane];
    const float attd = att_dst[lane];

    for (int nb = blockIdx.x * 16; nb < N; nb += gridDim.x * 16) {
        __syncthreads();
        for (int i = tid; i < 512; i += 256) {
            int r = i >> 5, k4 = i & 31;
            int node = nb + r;
            if (node < N)
                reinterpret_cast<float4*>(xl[r])[k4] =
                    reinterpret_cast<const float4*>(x + (size_t)node * 128)[k4];
        }
        __syncthreads();

        float acc0 = 0.f, acc1 = 0.f, acc2 = 0.f, acc3 = 0.f;
        const int r0 = wi * 4;
        const float4* xr0 = reinterpret_cast<const float4*>(xl[r0 + 0]);
        const float4* xr1 = reinterpret_cast<const float4*>(xl[r0 + 1]);
        const float4* xr2 = reinterpret_cast<const float4*>(xl[r0 + 2]);
        const float4* xr3 = reinterpret_cast<const float4*>(xl[r0 + 3]);
        #pragma unroll 4
        for (int k4 = 0; k4 < 32; ++k4) {
            float4 x0 = xr0[k4];   // broadcast reads (same addr across lanes)
            float4 x1 = xr1[k4];
            float4 x2 = xr2[k4];
            float4 x3 = xr3[k4];
            const int kb = k4 * 4;
            float wa = Wl[(kb + 0) * 64 + lane];
            float wb = Wl[(kb + 1) * 64 + lane];
            float wc = Wl[(kb + 2) * 64 + lane];
            float wd = Wl[(kb + 3) * 64 + lane];
            acc0 += x0.x * wa + x0.y * wb + x0.z * wc + x0.w * wd;
            acc1 += x1.x * wa + x1.y * wb + x1.z * wc + x1.w * wd;
            acc2 += x2.x * wa + x2.y * wb + x2.z * wc + x2.w * wd;
            acc3 += x3.x * wa + x3.y * wb + x3.z * wc + x3.w * wd;
        }

        float accs[4] = {acc0, acc1, acc2, acc3};
        #pragma unroll
        for (int j = 0; j < 4; ++j) {
            int node = nb + r0 + j;
            if (node < N) {
                h[(size_t)node * 64 + lane] = accs[j];
                float vs = accs[j] * atts;
                float vd = accs[j] * attd;
                vs += __shfl_xor(vs, 1, 64); vd += __shfl_xor(vd, 1, 64);
                vs += __shfl_xor(vs, 2, 64); vd += __shfl_xor(vd, 2, 64);
                vs += __shfl_xor(vs, 4, 64); vd += __shfl_xor(vd, 4, 64);
                if ((lane & 7) == 0) {
                    a_src[node * 8 + (lane >> 3)] = vs;
                    a_dst[node * 8 + (lane >> 3)] = vd;
                }
            }
        }
    }
}

// ---------------- CSR build ----------------
__global__ __launch_bounds__(256) void gat_hist(
    const int* __restrict__ e_dst, int* __restrict__ deg, int E)
{
    int i = blockIdx.x * 256 + threadIdx.x;
    int b = i * 4;
    if (b + 3 < E) {
        int4 d = *reinterpret_cast<const int4*>(e_dst + b);
        atomicAdd(&deg[d.x], 1);
        atomicAdd(&deg[d.y], 1);
        atomicAdd(&deg[d.z], 1);
        atomicAdd(&deg[d.w], 1);
    } else {
        for (int k = b; k < E; ++k) atomicAdd(&deg[e_dst[k]], 1);
    }
}

// Per-chunk (1024 elems) exclusive scan; chunkSum[b] = chunk total.
__global__ __launch_bounds__(256) void gat_scan_chunks(
    const int* __restrict__ deg, int* __restrict__ off,
    int* __restrict__ chunkSum, int N)
{
    __shared__ int lds[256];
    const int t = threadIdx.x;
    const int base = blockIdx.x * 1024 + t * 4;
    int v0 = 0, v1 = 0, v2 = 0, v3 = 0;
    if (base + 0 < N) v0 = deg[base + 0];
    if (base + 1 < N) v1 = deg[base + 1];
    if (base + 2 < N) v2 = deg[base + 2];
    if (base + 3 < N) v3 = deg[base + 3];
    int s = v0 + v1 + v2 + v3;
    lds[t] = s;
    __syncthreads();
    #pragma unroll
    for (int d = 1; d < 256; d <<= 1) {
        int add = (t >= d) ? lds[t - d] : 0;
        __syncthreads();
        lds[t] += add;
        __syncthreads();
    }
    if (t == 255) chunkSum[blockIdx.x] = lds[255];
    int p = lds[t] - s;  // exclusive within chunk
    if (base + 0 < N) off[base + 0] = p; p += v0;
    if (base + 1 < N) off[base + 1] = p; p += v1;
    if (base + 2 < N) off[base + 2] = p; p += v2;
    if (base + 3 < N) off[base + 3] = p;
}

// Exclusive scan of chunk sums (nChunks <= 128) in one 128-thread block.
__global__ __launch_bounds__(128) void gat_scan_tops(
    const int* __restrict__ chunkSum, int* __restrict__ chunkBase,
    int* __restrict__ off, int nChunks, int N)
{
    __shared__ int lds[128];
    const int t = threadIdx.x;
    if (nChunks > 128) {               // safety fallback (not hit at N=100k)
        if (t == 0) {
            int run = 0;
            for (int i = 0; i < nChunks; ++i) { chunkBase[i] = run; run += chunkSum[i]; }
            off[N] = run;
        }
        return;
    }
    int v = (t < nChunks) ? chunkSum[t] : 0;
    lds[t] = v;
    __syncthreads();
    #pragma unroll
    for (int d = 1; d < 128; d <<= 1) {
        int add = (t >= d) ? lds[t - d] : 0;
        __syncthreads();
        lds[t] += add;
        __syncthreads();
    }
    if (t < nChunks) chunkBase[t] = lds[t] - v;
    if (t == nChunks - 1) off[N] = lds[t];
}

__global__ __launch_bounds__(256) void gat_add_base(
    int* __restrict__ off, int* __restrict__ cursor,
    const int* __restrict__ chunkBase, int N)
{
    int i = blockIdx.x * 256 + threadIdx.x;
    if (i < N) {
        int v = off[i] + chunkBase[i >> 10];
        off[i] = v;
        cursor[i] = v;
    }
}

// dst-range-partitioned fill. Grid = nChunksE * 8 blocks; range = bid & 7
// (XCD-affine under round-robin block->XCD mapping). Each block scans one
// 1024-edge chunk (256 thr x 4) and scatters only edges whose dst lies in
// its N/8 range, so each range's esrc slice (~0.8 MB) stays cache-resident
// and bucket lines fully accumulate before eviction. Edge re-reads (8x) L3.
__global__ __launch_bounds__(256) void gat_fill(
    const int* __restrict__ e_src, const int* __restrict__ e_dst,
    int* __restrict__ cursor, int* __restrict__ esrc, int E, int N)
{
    const int range = blockIdx.x & 7;
    const int chunk = blockIdx.x >> 3;
    const int lo = (int)(((long long)N * range) >> 3);
    const int hi = (int)(((long long)N * (range + 1)) >> 3);

    const int b = chunk * 1024 + threadIdx.x * 4;
    if (b + 3 < E) {
        int4 sv = *reinterpret_cast<const int4*>(e_src + b);
        int4 dv = *reinterpret_cast<const int4*>(e_dst + b);
        if (dv.x >= lo && dv.x < hi) esrc[atomicAdd(&cursor[dv.x], 1)] = sv.x;
        if (dv.y >= lo && dv.y < hi) esrc[atomicAdd(&cursor[dv.y], 1)] = sv.y;
        if (dv.z >= lo && dv.z < hi) esrc[atomicAdd(&cursor[dv.z], 1)] = sv.z;
        if (dv.w >= lo && dv.w < hi) esrc[atomicAdd(&cursor[dv.w], 1)] = sv.w;
    } else {
        for (int k = b; k < E; ++k) {
            int d = e_dst[k];
            if (d >= lo && d < hi) esrc[atomicAdd(&cursor[d], 1)] = e_src[k];
        }
    }
}

// ---------------- Kernel 2: gather + softmax + ELU ----------------
// One wave per dst node; lane = head*8 + f. Fully-masked unroll-8 batches:
// tail edges use clamped index (always-valid load) with weight zeroed.
__global__ __launch_bounds__(256) void gat_gather(
    const int* __restrict__ off, const int* __restrict__ esrc,
    const float* __restrict__ h, const float* __restrict__ a_src,
    const float* __restrict__ a_dst, const float* __restrict__ bias,
    float* __restrict__ out, int N)
{
    const int node = blockIdx.x * 4 + (threadIdx.x >> 6);
    if (node >= N) return;
    const int lane = threadIdx.x & 63;
    const int head = lane >> 3;

    const float ad = a_dst[node * 8 + head];
    // self-loop
    float e0 = a_src[node * 8 + head] + ad;
    e0 = e0 > 0.f ? e0 : 0.2f * e0;
    float w0 = __expf(e0);
    float acc = w0 * h[(size_t)node * 64 + lane];
    float s = w0;

    const int beg = off[node], end = off[node + 1];
    for (int k = beg; k < end; k += 8) {
        int   sb[8];
        float ab[8], hb[8];
        #pragma unroll
        for (int u = 0; u < 8; ++u) {
            int kk = k + u;
            sb[u] = esrc[kk < end ? kk : end - 1];
        }
        #pragma unroll
        for (int u = 0; u < 8; ++u) ab[u] = a_src[sb[u] * 8 + head];
        #pragma unroll
        for (int u = 0; u < 8; ++u) hb[u] = h[(size_t)sb[u] * 64 + lane];
        #pragma unroll
        for (int u = 0; u < 8; ++u) {
            float a = ab[u] + ad;
            a = a > 0.f ? a : 0.2f * a;
            float w = (k + u < end) ? __expf(a) : 0.f;
            acc += w * hb[u];
            s += w;
        }
    }

    float v = acc / (s + 1e-16f) + bias[lane];
    out[(size_t)node * 64 + lane] = v > 0.f ? v : expm1f(v);
}

extern "C" void kernel_launch(void* const* d_in, const int* in_sizes, int n_in,
                              void* d_out, int out_size, void* d_ws, size_t ws_size,
                              hipStream_t stream)
{
    const float* x       = (const float*)d_in[0];
    const float* W       = (const float*)d_in[1];
    const float* att_src = (const float*)d_in[2];
    const float* att_dst = (const float*)d_in[3];
    const float* bias    = (const float*)d_in[4];
    const int*   ei      = (const int*)d_in[5];   // int32 (JAX x64 disabled)

    const int N = in_sizes[0] / 128;
    const int E = in_sizes[5] / 2;
    const int nChunks = (N + 1023) / 1024;

    float* out = (float*)d_out;

    // workspace layout (all 4-byte elems)
    float* h        = (float*)d_ws;                    // N*64
    float* a_src    = h + (size_t)N * 64;              // N*8
    float* a_dst    = a_src + (size_t)N * 8;           // N*8
    int*   deg      = (int*)(a_dst + (size_t)N * 8);   // N
    int*   off      = deg + N;                         // N+1
    int*   cursor   = off + N + 1;                     // N
    int*   chunkSum = cursor + N;                      // nChunks
    int*   chunkBase= chunkSum + nChunks;              // nChunks
    int*   esrc     = chunkBase + nChunks;             // E

    const int* e_src = ei;
    const int* e_dst = ei + E;

    hipMemsetAsync(deg, 0, (size_t)N * sizeof(int), stream);

    gat_linear<<<1024, 256, 0, stream>>>(x, W, att_src, att_dst, h, a_src, a_dst, N);

    int eb4 = (E / 4 + 256) / 256;
    gat_hist<<<eb4, 256, 0, stream>>>(e_dst, deg, E);
    gat_scan_chunks<<<nChunks, 256, 0, stream>>>(deg, off, chunkSum, N);
    gat_scan_tops<<<1, 128, 0, stream>>>(chunkSum, chunkBase, off, nChunks, N);
    gat_add_base<<<(N + 255) / 256, 256, 0, stream>>>(off, cursor, chunkBase, N);

    int nChunksE = (E + 1023) / 1024;
    gat_fill<<<nChunksE * 8, 256, 0, stream>>>(e_src, e_dst, cursor, esrc, E, N);

    gat_gather<<<(N + 3) / 4, 256, 0, stream>>>(off, esrc, h, a_src, a_dst, bias, out, N);
}